// Round 9
// baseline (221.857 us; speedup 1.0000x reference)
//
#include <hip/hip_runtime.h>
#include <hip/hip_bf16.h>
#include <stdint.h>

#define D_IN 1024
#define NH 16
#define DH 64
#define SEQ 2048
#define BATCH 2

typedef unsigned short u16;
typedef __attribute__((ext_vector_type(8))) short short8;
typedef __attribute__((ext_vector_type(4))) float f32x4;

#define CSCALE 0.1803368801f   // 0.125 * log2(e), folded into Q

__device__ __forceinline__ u16 f2bf(float f) {
    union { float f; uint32_t u; } v; v.f = f;
    uint32_t r = v.u + 0x7FFF + ((v.u >> 16) & 1);
    return (u16)(r >> 16);
}

__device__ __forceinline__ float bf2f(u16 u) {
    union { uint32_t u; float f; } v; v.u = (uint32_t)u << 16;
    return v.f;
}

// pack two fp32 -> two bf16 (truncate) in ONE v_perm_b32
__device__ __forceinline__ uint32_t pktrunc(float a, float b) {
    union { float f; uint32_t u; } x, y;
    x.f = a; y.f = b;
    return __builtin_amdgcn_perm(y.u, x.u, 0x07060302u);
}

__device__ __forceinline__ void async16(const u16* g, u16* l) {
    __builtin_amdgcn_global_load_lds(
        (const __attribute__((address_space(1))) void*)g,
        (__attribute__((address_space(3))) void*)l, 16, 0, 0);
}

// ---- fused prep: x cast (0..4095) + W transpose/cast (4096..4863) + flag zero ----
__global__ __launch_bounds__(256) void prep_kernel(
    const float* __restrict__ x, const float* __restrict__ Wq,
    const float* __restrict__ Wk, const float* __restrict__ Wv,
    u16* __restrict__ xb, u16* __restrict__ WT, int* __restrict__ flags)
{
    __shared__ float tile[64][65];
    if (blockIdx.x >= 4864) {
        if (threadIdx.x < 256) flags[threadIdx.x] = 0;
        return;
    }
    if (blockIdx.x < 4096) {
        int i = (blockIdx.x * 256 + threadIdx.x) * 4;
        float4 v = *(const float4*)(x + i);
        union { u16 u[4]; uint2 d; } o;
        o.u[0] = f2bf(v.x); o.u[1] = f2bf(v.y); o.u[2] = f2bf(v.z); o.u[3] = f2bf(v.w);
        *(uint2*)(xb + i) = o.d;
        return;
    }
    int idx = blockIdx.x - 4096;
    int mat = idx >> 8, rem = idx & 255;
    int k0 = (rem & 15) * 64, n0 = (rem >> 4) * 64;
    const float* W = (mat == 0) ? Wq : (mat == 1 ? Wk : Wv);
    int c = threadIdx.x & 63, rb = threadIdx.x >> 6;
    #pragma unroll
    for (int p = 0; p < 16; ++p) {
        int r = p * 4 + rb;
        tile[r][c] = W[(size_t)(k0 + r) * 1024 + n0 + c];
    }
    __syncthreads();
    #pragma unroll
    for (int p = 0; p < 16; ++p) {
        int r = p * 4 + rb;
        WT[((size_t)mat * 1024 + n0 + r) * 1024 + k0 + c] = f2bf(tile[c][r]);
    }
}

// ---- fused QKV GEMM: BK=64, XOR-swizzled LDS (conflict-free), V transposed ----
__global__ __launch_bounds__(256) void qkv_gemm_kernel(
    const u16* __restrict__ xb, const u16* __restrict__ WT,
    const float* __restrict__ bq, const float* __restrict__ bk,
    const float* __restrict__ bv,
    u16* __restrict__ Qb, u16* __restrict__ Kb, u16* __restrict__ Vt)
{
    __shared__ u16 smem[4 * 64 * 72];   // 36 KB; k-loop uses 32 KB (As+Bs)
    u16* As = smem;                     // [128][64], chunk-swizzled
    u16* Bs = smem + 128 * 64;
    const int tid  = threadIdx.x;
    const int wave = tid >> 6, lane = tid & 63;
    const int quad = lane >> 4, l15 = lane & 15;
    const int m0 = blockIdx.y * 128;
    const int n0 = blockIdx.x * 128;

    f32x4 acc[4][4];
    #pragma unroll
    for (int i = 0; i < 4; ++i)
        #pragma unroll
        for (int j = 0; j < 4; ++j)
            acc[i][j] = (f32x4){0.f, 0.f, 0.f, 0.f};

    const int wm = wave & 1, wn = wave >> 1;
    const int srow8 = tid >> 3;        // 0..31
    const int sslot = tid & 7;
    const int fsig  = l15 & 7;         // fragment-row swizzle key

    for (int k0 = 0; k0 < 1024; k0 += 64) {
        #pragma unroll
        for (int rnd = 0; rnd < 4; ++rnd) {
            int row = rnd * 32 + srow8;
            int g = sslot ^ (row & 7);
            async16(xb + (size_t)(m0 + row) * 1024 + k0 + g * 8, As + rnd * 2048 + tid * 8);
            async16(WT + (size_t)(n0 + row) * 1024 + k0 + g * 8, Bs + rnd * 2048 + tid * 8);
        }
        __syncthreads();
        #pragma unroll
        for (int kk = 0; kk < 2; ++kk) {
            short8 af[4], bfr[4];
            #pragma unroll
            for (int f = 0; f < 4; ++f) {
                int slot = ((kk << 2) + quad) ^ fsig;
                af[f]  = *(const short8*)(As + (wm * 64 + f * 16 + l15) * 64 + slot * 8);
                bfr[f] = *(const short8*)(Bs + (wn * 64 + f * 16 + l15) * 64 + slot * 8);
            }
            #pragma unroll
            for (int i = 0; i < 4; ++i)
                #pragma unroll
                for (int j = 0; j < 4; ++j)
                    acc[i][j] = __builtin_amdgcn_mfma_f32_16x16x32_bf16(af[i], bfr[j], acc[i][j], 0, 0, 0);
        }
        __syncthreads();
    }

    const int mat = n0 >> 10;
    const int ncb = (n0 & 1023) + wn * 64;   // multiple of 64
    const int hh = ncb >> 6;
    const int bb = m0 >> 11, sb = m0 & 2047;

    if (mat < 2) {
        const float* bias = (mat == 0) ? bq : bk;
        u16* dst = (mat == 0) ? Qb : Kb;
        const float sc = (mat == 0) ? CSCALE : 1.0f;
        #pragma unroll
        for (int i = 0; i < 4; ++i) {
            int ss = sb + wm * 64 + i * 16 + quad * 4;
            #pragma unroll
            for (int j = 0; j < 4; ++j) {
                int dh = j * 16 + l15;
                float bval = bias[ncb + dh];
                size_t base = (((size_t)bb * NH + hh) * SEQ + ss) * DH + dh;
                #pragma unroll
                for (int r = 0; r < 4; ++r)
                    dst[base + (size_t)r * DH] = f2bf((acc[i][j][r] + bval) * sc);
            }
        }
    } else {
        // V: per-wave LDS transpose (smem free after final barrier), b128 stores
        u16* vt = smem + wave * (64 * 72);   // [dh][m], stride 72
        #pragma unroll
        for (int i = 0; i < 4; ++i)
            #pragma unroll
            for (int j = 0; j < 4; ++j) {
                float bval = bv[ncb + j * 16 + l15];
                union { u16 u[4]; uint2 d; } o;
                #pragma unroll
                for (int r = 0; r < 4; ++r)
                    o.u[r] = f2bf(acc[i][j][r] + bval);
                *(uint2*)(vt + (j * 16 + l15) * 72 + i * 16 + quad * 4) = o.d;
            }
        const int s0w = sb + wm * 64;
        u16* vdst = Vt + ((size_t)(bb * NH + hh) * DH) * SEQ;
        #pragma unroll
        for (int it = 0; it < 8; ++it) {
            int dh = it * 8 + (lane >> 3);
            short8 v = *(const short8*)(vt + dh * 72 + (lane & 7) * 8);
            *(short8*)(vdst + (size_t)dh * SEQ + s0w + (lane & 7) * 8) = v;
        }
    }
}

// ---- stage one 64x64 bf16 tile into LDS, swizzle sigma(row)=4*((row>>3)&1)+(row&3) ----
__device__ __forceinline__ void stage64(const u16* g0, size_t gstride, u16* lds,
                                        int wave, int lane)
{
    #pragma unroll
    for (int rnd = 0; rnd < 2; ++rnd) {
        int row = rnd * 32 + wave * 8 + (lane >> 3);
        int sig = ((row >> 3) & 1) * 4 + (row & 3);
        int c = (lane & 7) ^ sig;
        async16(g0 + (size_t)row * gstride + c * 8, lds + row * 64 + (lane & 7) * 8);
    }
}

// ---- flash attention (causal), key-split jobs, in-lane P, fused combine ----
__global__ __launch_bounds__(256) void flash_mfma_kernel(
    const u16* __restrict__ Qb, const u16* __restrict__ Kb,
    const u16* __restrict__ Vt, float* __restrict__ out,
    u16* __restrict__ Opart, float* __restrict__ Lpart, int* __restrict__ flags)
{
    static const int JQT[24] = {7,15,15,14,14, 6,13,13,12,12, 5,11,11,10,10,
                                4, 9, 9, 8, 8, 3, 2, 1, 0};
    static const int JHF[24] = {-1,0,1,0,1, -1,0,1,0,1, -1,0,1,0,1,
                                -1,0,1,0,1, -1,-1,-1,-1};

    __shared__ u16 Ks[2][64 * 64];   // [key][dh], sigma-swizzled chunks
    __shared__ u16 Vs[2][64 * 64];   // [dh][key], sigma-swizzled chunks
    __shared__ int doComb;

    const int tid  = threadIdx.x;
    const int wave = tid >> 6, lane = tid & 63;
    const int quad = lane >> 4, l15 = lane & 15;
    const int bhx = blockIdx.x;                 // 0..31
    const int b = bhx >> 4, h = bhx & 15;
    const int job = blockIdx.y;                 // 0..23, heaviest-first
    const int qt = JQT[job], hf = JHF[job];
    const int t0 = (hf == 1) ? qt + 1 : 0;
    const int t1 = (hf == 0) ? qt + 1 : 2 * qt + 2;
    const int q0 = qt * 128;
    const int wq0 = wave * 32;
    const size_t bh = (size_t)bhx;
    const u16* Qp = Qb + bh * SEQ * DH;
    const u16* Kp = Kb + bh * SEQ * DH;
    const u16* Vp = Vt + bh * DH * SEQ;

    // Q as B-operand fragments
    short8 qf[2][2];
    #pragma unroll
    for (int qa = 0; qa < 2; ++qa) {
        const u16* qrp = Qp + (size_t)(q0 + wq0 + qa * 16 + l15) * DH;
        qf[qa][0] = *(const short8*)(qrp + quad * 8);
        qf[qa][1] = *(const short8*)(qrp + 32 + quad * 8);
    }

    const short8 ones = (short8){0x3F80, 0x3F80, 0x3F80, 0x3F80,
                                 0x3F80, 0x3F80, 0x3F80, 0x3F80};  // bf16 1.0

    f32x4 O[2][4], L[2];
    #pragma unroll
    for (int pa = 0; pa < 2; ++pa) {
        #pragma unroll
        for (int f = 0; f < 4; ++f) O[pa][f] = (f32x4){0.f, 0.f, 0.f, 0.f};
        L[pa] = (f32x4){0.f, 0.f, 0.f, 0.f};
    }

    const int wqmax = q0 + wq0 + 31;
    const int krbase = (l15 >> 2) * 8 + (l15 & 3);
    const int ksig   = ((l15 >> 2) & 1) * 4 + (l15 & 3);
    const int vsig   = ((l15 >> 3) & 1) * 4 + (l15 & 3);

    stage64(Kp + (size_t)t0 * 64 * DH, DH, Ks[t0 & 1], wave, lane);
    stage64(Vp + t0 * 64, SEQ, Vs[t0 & 1], wave, lane);
    __syncthreads();

    for (int t = t0; t < t1; ++t) {
        const int cur = t & 1;
        if (t + 1 < t1) {
            int k1 = (t + 1) * 64;
            stage64(Kp + (size_t)k1 * DH, DH, Ks[cur ^ 1], wave, lane);
            stage64(Vp + k1, SEQ, Vs[cur ^ 1], wave, lane);
        }
        const int k0 = t * 64;
        if (k0 <= wqmax) {
            // S^T = K Q^T with permuted K rows
            f32x4 sf[4][2];
            #pragma unroll
            for (int fj = 0; fj < 4; ++fj) {
                int krow = (fj >> 1) * 32 + krbase + (fj & 1) * 4;
                const u16* kp = &Ks[cur][krow * 64];
                short8 k0f = *(const short8*)(kp + (quad ^ ksig) * 8);
                short8 k1f = *(const short8*)(kp + ((4 + quad) ^ ksig) * 8);
                #pragma unroll
                for (int qa = 0; qa < 2; ++qa) {
                    f32x4 s = (f32x4){0.f, 0.f, 0.f, 0.f};
                    s = __builtin_amdgcn_mfma_f32_16x16x32_bf16(k0f, qf[qa][0], s, 0, 0, 0);
                    s = __builtin_amdgcn_mfma_f32_16x16x32_bf16(k1f, qf[qa][1], s, 0, 0, 0);
                    sf[fj][qa] = s;
                }
            }
            const bool diag = (k0 + 63 > q0 + wq0);
            short8 pA[2][2];
            #pragma unroll
            for (int qa = 0; qa < 2; ++qa) {
                #pragma unroll
                for (int fj = 0; fj < 4; ++fj)
                    #pragma unroll
                    for (int r = 0; r < 4; ++r) {
                        float p = __builtin_amdgcn_exp2f(sf[fj][qa][r]);
                        if (diag) {
                            int key = k0 + (fj >> 1) * 32 + quad * 8 + (fj & 1) * 4 + r;
                            int qg  = q0 + wq0 + qa * 16 + l15;
                            p = (key <= qg) ? p : 0.f;
                        }
                        sf[fj][qa][r] = p;
                    }
                union { uint32_t d[4]; short8 v; } a0, a1;
                a0.d[0] = pktrunc(sf[0][qa][0], sf[0][qa][1]);
                a0.d[1] = pktrunc(sf[0][qa][2], sf[0][qa][3]);
                a0.d[2] = pktrunc(sf[1][qa][0], sf[1][qa][1]);
                a0.d[3] = pktrunc(sf[1][qa][2], sf[1][qa][3]);
                a1.d[0] = pktrunc(sf[2][qa][0], sf[2][qa][1]);
                a1.d[1] = pktrunc(sf[2][qa][2], sf[2][qa][3]);
                a1.d[2] = pktrunc(sf[3][qa][0], sf[3][qa][1]);
                a1.d[3] = pktrunc(sf[3][qa][2], sf[3][qa][3]);
                pA[qa][0] = a0.v;
                pA[qa][1] = a1.v;
                L[qa] = __builtin_amdgcn_mfma_f32_16x16x32_bf16(pA[qa][0], ones, L[qa], 0, 0, 0);
                L[qa] = __builtin_amdgcn_mfma_f32_16x16x32_bf16(pA[qa][1], ones, L[qa], 0, 0, 0);
            }
            #pragma unroll
            for (int fo = 0; fo < 4; ++fo) {
                const u16* vrow = &Vs[cur][(fo * 16 + l15) * 64];
                short8 vb0 = *(const short8*)(vrow + (quad ^ vsig) * 8);
                short8 vb1 = *(const short8*)(vrow + ((4 + quad) ^ vsig) * 8);
                #pragma unroll
                for (int pa = 0; pa < 2; ++pa) {
                    O[pa][fo] = __builtin_amdgcn_mfma_f32_16x16x32_bf16(pA[pa][0], vb0, O[pa][fo], 0, 0, 0);
                    O[pa][fo] = __builtin_amdgcn_mfma_f32_16x16x32_bf16(pA[pa][1], vb1, O[pa][fo], 0, 0, 0);
                }
            }
        }
        __syncthreads();
    }

    if (hf < 0) {
        #pragma unroll
        for (int pa = 0; pa < 2; ++pa)
            #pragma unroll
            for (int fo = 0; fo < 4; ++fo)
                #pragma unroll
                for (int r = 0; r < 4; ++r) {
                    int s = q0 + wq0 + pa * 16 + quad * 4 + r;
                    out[((size_t)b * SEQ + s) * 1024 + h * DH + fo * 16 + l15] =
                        O[pa][fo][r] / L[pa][r];
                }
        return;
    }

    // write partials
    const int pi = (qt - 8) * 2 + hf;
    u16* op = Opart + (((size_t)pi * 32 + bhx) * 128) * 64;
    float* lp = Lpart + ((size_t)pi * 32 + bhx) * 128;
    #pragma unroll
    for (int pa = 0; pa < 2; ++pa) {
        #pragma unroll
        for (int fo = 0; fo < 4; ++fo)
            #pragma unroll
            for (int r = 0; r < 4; ++r) {
                int ql = wq0 + pa * 16 + quad * 4 + r;
                op[(size_t)ql * 64 + fo * 16 + l15] = f2bf(O[pa][fo][r]);
            }
        if (l15 == 0) {
            #pragma unroll
            for (int r = 0; r < 4; ++r)
                lp[wq0 + pa * 16 + quad * 4 + r] = L[pa][r];
        }
    }

    // fused combine: second finisher of the pair does (O0+O1)/(l0+l1)
    __syncthreads();                 // drains vmcnt(0): all partial stores done
    if (tid == 0) {
        __threadfence();             // device-scope release
        doComb = atomicAdd(&flags[(qt - 8) * 32 + bhx], 1);
    }
    __syncthreads();
    if (doComb == 1) {
        __threadfence();             // device-scope acquire
        const int pi0 = (qt - 8) * 2, pi1 = pi0 + 1;
        const int q = tid >> 1, seg = (tid & 1) * 32;
        const u16* o0 = Opart + (((size_t)pi0 * 32 + bhx) * 128 + q) * 64 + seg;
        const u16* o1 = Opart + (((size_t)pi1 * 32 + bhx) * 128 + q) * 64 + seg;
        float inv = 1.0f / (Lpart[((size_t)pi0 * 32 + bhx) * 128 + q] +
                            Lpart[((size_t)pi1 * 32 + bhx) * 128 + q]);
        float* opf = out + ((size_t)b * SEQ + qt * 128 + q) * 1024 + h * DH + seg;
        #pragma unroll
        for (int d = 0; d < 32; d += 4) {
            union { uint2 d2; u16 u[4]; } a, c;
            a.d2 = *(const uint2*)(o0 + d);
            c.d2 = *(const uint2*)(o1 + d);
            float4 v;
            v.x = (bf2f(a.u[0]) + bf2f(c.u[0])) * inv;
            v.y = (bf2f(a.u[1]) + bf2f(c.u[1])) * inv;
            v.z = (bf2f(a.u[2]) + bf2f(c.u[2])) * inv;
            v.w = (bf2f(a.u[3]) + bf2f(c.u[3])) * inv;
            *(float4*)(opf + d) = v;
        }
    }
}

extern "C" void kernel_launch(void* const* d_in, const int* in_sizes, int n_in,
                              void* d_out, int out_size, void* d_ws, size_t ws_size,
                              hipStream_t stream) {
    const float* x  = (const float*)d_in[0];
    const float* Wq = (const float*)d_in[1];
    const float* bq = (const float*)d_in[2];
    const float* Wk = (const float*)d_in[3];
    const float* bk = (const float*)d_in[4];
    const float* Wv = (const float*)d_in[5];
    const float* bv = (const float*)d_in[6];
    float* out = (float*)d_out;

    const size_t NX = (size_t)BATCH * SEQ * D_IN;    // 4M
    const size_t NW = (size_t)3 * D_IN * 1024;       // 3M
    const size_t NP = (size_t)BATCH * NH * SEQ * DH; // 4M
    u16* xb = (u16*)d_ws;
    u16* WT = xb + NX;
    u16* Qb = WT + NW;
    u16* Kb = Qb + NP;
    u16* Vt = Kb + NP;
    int* flags = (int*)(Vt + NP);        // 256 ints, after all live regions
    // partials alias xb/WT (dead after qkv_gemm): Opart 8 MB, Lpart 256 KB
    u16* Opart = xb;
    float* Lpart = (float*)(xb + NX);    // = WT start

    prep_kernel<<<4096 + 768 + 1, 256, 0, stream>>>(x, Wq, Wk, Wv, xb, WT, flags);
    qkv_gemm_kernel<<<dim3(24, 32), 256, 0, stream>>>(xb, WT, bq, bk, bv, Qb, Kb, Vt);
    flash_mfma_kernel<<<dim3(32, 24), 256, 0, stream>>>(Qb, Kb, Vt, out, Opart, Lpart, flags);
}

// Round 10
// 162.345 us; speedup vs baseline: 1.3666x; 1.3666x over previous
//
#include <hip/hip_runtime.h>
#include <hip/hip_bf16.h>
#include <stdint.h>

#define D_IN 1024
#define NH 16
#define DH 64
#define SEQ 2048
#define BATCH 2

typedef unsigned short u16;
typedef __attribute__((ext_vector_type(8))) short short8;
typedef __attribute__((ext_vector_type(4))) float f32x4;

#define CSCALE 0.1803368801f   // 0.125 * log2(e), folded into Q

__device__ __forceinline__ u16 f2bf(float f) {
    union { float f; uint32_t u; } v; v.f = f;
    uint32_t r = v.u + 0x7FFF + ((v.u >> 16) & 1);
    return (u16)(r >> 16);
}

__device__ __forceinline__ float bf2f(u16 u) {
    union { uint32_t u; float f; } v; v.u = (uint32_t)u << 16;
    return v.f;
}

// pack two fp32 -> two bf16 (truncate) in ONE v_perm_b32
__device__ __forceinline__ uint32_t pktrunc(float a, float b) {
    union { float f; uint32_t u; } x, y;
    x.f = a; y.f = b;
    return __builtin_amdgcn_perm(y.u, x.u, 0x07060302u);
}

__device__ __forceinline__ void async16(const u16* g, u16* l) {
    __builtin_amdgcn_global_load_lds(
        (const __attribute__((address_space(1))) void*)g,
        (__attribute__((address_space(3))) void*)l, 16, 0, 0);
}

// ---- fused prep: x fp32->bf16 cast (blocks 0..4095) + W transpose/cast ----
__global__ __launch_bounds__(256) void prep_kernel(
    const float* __restrict__ x, const float* __restrict__ Wq,
    const float* __restrict__ Wk, const float* __restrict__ Wv,
    u16* __restrict__ xb, u16* __restrict__ WT)
{
    __shared__ float tile[64][65];
    if (blockIdx.x < 4096) {
        int i = (blockIdx.x * 256 + threadIdx.x) * 4;
        float4 v = *(const float4*)(x + i);
        union { u16 u[4]; uint2 d; } o;
        o.u[0] = f2bf(v.x); o.u[1] = f2bf(v.y); o.u[2] = f2bf(v.z); o.u[3] = f2bf(v.w);
        *(uint2*)(xb + i) = o.d;
        return;
    }
    int idx = blockIdx.x - 4096;
    int mat = idx >> 8, rem = idx & 255;
    int k0 = (rem & 15) * 64, n0 = (rem >> 4) * 64;
    const float* W = (mat == 0) ? Wq : (mat == 1 ? Wk : Wv);
    int c = threadIdx.x & 63, rb = threadIdx.x >> 6;
    #pragma unroll
    for (int p = 0; p < 16; ++p) {
        int r = p * 4 + rb;
        tile[r][c] = W[(size_t)(k0 + r) * 1024 + n0 + c];
    }
    __syncthreads();
    #pragma unroll
    for (int p = 0; p < 16; ++p) {
        int r = p * 4 + rb;
        WT[((size_t)mat * 1024 + n0 + r) * 1024 + k0 + c] = f2bf(tile[c][r]);
    }
}

// ---- fused QKV GEMM: BK=64, XOR-swizzled LDS (conflict-free), V transposed ----
__global__ __launch_bounds__(256) void qkv_gemm_kernel(
    const u16* __restrict__ xb, const u16* __restrict__ WT,
    const float* __restrict__ bq, const float* __restrict__ bk,
    const float* __restrict__ bv,
    u16* __restrict__ Qb, u16* __restrict__ Kb, u16* __restrict__ Vt)
{
    __shared__ u16 smem[4 * 64 * 72];   // 36 KB; k-loop uses 32 KB (As+Bs)
    u16* As = smem;                     // [128][64], chunk-swizzled
    u16* Bs = smem + 128 * 64;
    const int tid  = threadIdx.x;
    const int wave = tid >> 6, lane = tid & 63;
    const int quad = lane >> 4, l15 = lane & 15;
    const int m0 = blockIdx.y * 128;
    const int n0 = blockIdx.x * 128;

    f32x4 acc[4][4];
    #pragma unroll
    for (int i = 0; i < 4; ++i)
        #pragma unroll
        for (int j = 0; j < 4; ++j)
            acc[i][j] = (f32x4){0.f, 0.f, 0.f, 0.f};

    const int wm = wave & 1, wn = wave >> 1;
    const int srow8 = tid >> 3;        // 0..31
    const int sslot = tid & 7;
    const int fsig  = l15 & 7;         // fragment-row swizzle key

    for (int k0 = 0; k0 < 1024; k0 += 64) {
        #pragma unroll
        for (int rnd = 0; rnd < 4; ++rnd) {
            int row = rnd * 32 + srow8;
            int g = sslot ^ (row & 7);
            async16(xb + (size_t)(m0 + row) * 1024 + k0 + g * 8, As + rnd * 2048 + tid * 8);
            async16(WT + (size_t)(n0 + row) * 1024 + k0 + g * 8, Bs + rnd * 2048 + tid * 8);
        }
        __syncthreads();
        #pragma unroll
        for (int kk = 0; kk < 2; ++kk) {
            short8 af[4], bfr[4];
            #pragma unroll
            for (int f = 0; f < 4; ++f) {
                int slot = ((kk << 2) + quad) ^ fsig;
                af[f]  = *(const short8*)(As + (wm * 64 + f * 16 + l15) * 64 + slot * 8);
                bfr[f] = *(const short8*)(Bs + (wn * 64 + f * 16 + l15) * 64 + slot * 8);
            }
            #pragma unroll
            for (int i = 0; i < 4; ++i)
                #pragma unroll
                for (int j = 0; j < 4; ++j)
                    acc[i][j] = __builtin_amdgcn_mfma_f32_16x16x32_bf16(af[i], bfr[j], acc[i][j], 0, 0, 0);
        }
        __syncthreads();
    }

    const int mat = n0 >> 10;
    const int ncb = (n0 & 1023) + wn * 64;   // multiple of 64
    const int hh = ncb >> 6;
    const int bb = m0 >> 11, sb = m0 & 2047;

    if (mat < 2) {
        const float* bias = (mat == 0) ? bq : bk;
        u16* dst = (mat == 0) ? Qb : Kb;
        const float sc = (mat == 0) ? CSCALE : 1.0f;
        #pragma unroll
        for (int i = 0; i < 4; ++i) {
            int ss = sb + wm * 64 + i * 16 + quad * 4;
            #pragma unroll
            for (int j = 0; j < 4; ++j) {
                int dh = j * 16 + l15;
                float bval = bias[ncb + dh];
                size_t base = (((size_t)bb * NH + hh) * SEQ + ss) * DH + dh;
                #pragma unroll
                for (int r = 0; r < 4; ++r)
                    dst[base + (size_t)r * DH] = f2bf((acc[i][j][r] + bval) * sc);
            }
        }
    } else {
        // V: per-wave LDS transpose (smem free after final barrier), b128 stores
        u16* vt = smem + wave * (64 * 72);   // [dh][m], stride 72
        #pragma unroll
        for (int i = 0; i < 4; ++i)
            #pragma unroll
            for (int j = 0; j < 4; ++j) {
                float bval = bv[ncb + j * 16 + l15];
                union { u16 u[4]; uint2 d; } o;
                #pragma unroll
                for (int r = 0; r < 4; ++r)
                    o.u[r] = f2bf(acc[i][j][r] + bval);
                *(uint2*)(vt + (j * 16 + l15) * 72 + i * 16 + quad * 4) = o.d;
            }
        const int s0w = sb + wm * 64;
        u16* vdst = Vt + ((size_t)(bb * NH + hh) * DH) * SEQ;
        #pragma unroll
        for (int it = 0; it < 8; ++it) {
            int dh = it * 8 + (lane >> 3);
            short8 v = *(const short8*)(vt + dh * 72 + (lane & 7) * 8);
            *(short8*)(vdst + (size_t)dh * SEQ + s0w + (lane & 7) * 8) = v;
        }
    }
}

// ---- stage one 64x64 bf16 tile into LDS, swizzle sigma(row)=4*((row>>3)&1)+(row&3) ----
__device__ __forceinline__ void stage64(const u16* g0, size_t gstride, u16* lds,
                                        int wave, int lane)
{
    #pragma unroll
    for (int rnd = 0; rnd < 2; ++rnd) {
        int row = rnd * 32 + wave * 8 + (lane >> 3);
        int sig = ((row >> 3) & 1) * 4 + (row & 3);
        int c = (lane & 7) ^ sig;
        async16(g0 + (size_t)row * gstride + c * 8, lds + row * 64 + (lane & 7) * 8);
    }
}

// ---- flash attention (causal), key-split jobs, in-lane P (no LDS round-trip) ----
__global__ __launch_bounds__(256) void flash_mfma_kernel(
    const u16* __restrict__ Qb, const u16* __restrict__ Kb,
    const u16* __restrict__ Vt, float* __restrict__ out,
    u16* __restrict__ Opart, float* __restrict__ Lpart)
{
    static const int JQT[24] = {7,15,15,14,14, 6,13,13,12,12, 5,11,11,10,10,
                                4, 9, 9, 8, 8, 3, 2, 1, 0};
    static const int JHF[24] = {-1,0,1,0,1, -1,0,1,0,1, -1,0,1,0,1,
                                -1,0,1,0,1, -1,-1,-1,-1};

    __shared__ u16 Ks[2][64 * 64];   // [key][dh], sigma-swizzled chunks
    __shared__ u16 Vs[2][64 * 64];   // [dh][key], sigma-swizzled chunks

    const int tid  = threadIdx.x;
    const int wave = tid >> 6, lane = tid & 63;
    const int quad = lane >> 4, l15 = lane & 15;
    const int bhx = blockIdx.x;                 // 0..31
    const int b = bhx >> 4, h = bhx & 15;
    const int job = blockIdx.y;                 // 0..23, heaviest-first
    const int qt = JQT[job], hf = JHF[job];
    const int t0 = (hf == 1) ? qt + 1 : 0;
    const int t1 = (hf == 0) ? qt + 1 : 2 * qt + 2;
    const int q0 = qt * 128;
    const int wq0 = wave * 32;
    const size_t bh = (size_t)bhx;
    const u16* Qp = Qb + bh * SEQ * DH;
    const u16* Kp = Kb + bh * SEQ * DH;
    const u16* Vp = Vt + bh * DH * SEQ;

    // Q as B-operand fragments
    short8 qf[2][2];
    #pragma unroll
    for (int qa = 0; qa < 2; ++qa) {
        const u16* qrp = Qp + (size_t)(q0 + wq0 + qa * 16 + l15) * DH;
        qf[qa][0] = *(const short8*)(qrp + quad * 8);
        qf[qa][1] = *(const short8*)(qrp + 32 + quad * 8);
    }

    const short8 ones = (short8){0x3F80, 0x3F80, 0x3F80, 0x3F80,
                                 0x3F80, 0x3F80, 0x3F80, 0x3F80};  // bf16 1.0

    f32x4 O[2][4], L[2];
    #pragma unroll
    for (int pa = 0; pa < 2; ++pa) {
        #pragma unroll
        for (int f = 0; f < 4; ++f) O[pa][f] = (f32x4){0.f, 0.f, 0.f, 0.f};
        L[pa] = (f32x4){0.f, 0.f, 0.f, 0.f};
    }

    const int wqmax = q0 + wq0 + 31;
    const int krbase = (l15 >> 2) * 8 + (l15 & 3);
    const int ksig   = ((l15 >> 2) & 1) * 4 + (l15 & 3);
    const int vsig   = ((l15 >> 3) & 1) * 4 + (l15 & 3);

    stage64(Kp + (size_t)t0 * 64 * DH, DH, Ks[t0 & 1], wave, lane);
    stage64(Vp + t0 * 64, SEQ, Vs[t0 & 1], wave, lane);
    __syncthreads();

    for (int t = t0; t < t1; ++t) {
        const int cur = t & 1;
        if (t + 1 < t1) {
            int k1 = (t + 1) * 64;
            stage64(Kp + (size_t)k1 * DH, DH, Ks[cur ^ 1], wave, lane);
            stage64(Vp + k1, SEQ, Vs[cur ^ 1], wave, lane);
        }
        const int k0 = t * 64;
        if (k0 <= wqmax) {
            // S^T = K Q^T with permuted K rows
            f32x4 sf[4][2];
            #pragma unroll
            for (int fj = 0; fj < 4; ++fj) {
                int krow = (fj >> 1) * 32 + krbase + (fj & 1) * 4;
                const u16* kp = &Ks[cur][krow * 64];
                short8 k0f = *(const short8*)(kp + (quad ^ ksig) * 8);
                short8 k1f = *(const short8*)(kp + ((4 + quad) ^ ksig) * 8);
                #pragma unroll
                for (int qa = 0; qa < 2; ++qa) {
                    f32x4 s = (f32x4){0.f, 0.f, 0.f, 0.f};
                    s = __builtin_amdgcn_mfma_f32_16x16x32_bf16(k0f, qf[qa][0], s, 0, 0, 0);
                    s = __builtin_amdgcn_mfma_f32_16x16x32_bf16(k1f, qf[qa][1], s, 0, 0, 0);
                    sf[fj][qa] = s;
                }
            }
            const bool diag = (k0 + 63 > q0 + wq0);
            short8 pA[2][2];
            #pragma unroll
            for (int qa = 0; qa < 2; ++qa) {
                #pragma unroll
                for (int fj = 0; fj < 4; ++fj)
                    #pragma unroll
                    for (int r = 0; r < 4; ++r) {
                        float p = __builtin_amdgcn_exp2f(sf[fj][qa][r]);
                        if (diag) {
                            int key = k0 + (fj >> 1) * 32 + quad * 8 + (fj & 1) * 4 + r;
                            int qg  = q0 + wq0 + qa * 16 + l15;
                            p = (key <= qg) ? p : 0.f;
                        }
                        sf[fj][qa][r] = p;
                    }
                union { uint32_t d[4]; short8 v; } a0, a1;
                a0.d[0] = pktrunc(sf[0][qa][0], sf[0][qa][1]);
                a0.d[1] = pktrunc(sf[0][qa][2], sf[0][qa][3]);
                a0.d[2] = pktrunc(sf[1][qa][0], sf[1][qa][1]);
                a0.d[3] = pktrunc(sf[1][qa][2], sf[1][qa][3]);
                a1.d[0] = pktrunc(sf[2][qa][0], sf[2][qa][1]);
                a1.d[1] = pktrunc(sf[2][qa][2], sf[2][qa][3]);
                a1.d[2] = pktrunc(sf[3][qa][0], sf[3][qa][1]);
                a1.d[3] = pktrunc(sf[3][qa][2], sf[3][qa][3]);
                pA[qa][0] = a0.v;
                pA[qa][1] = a1.v;
                L[qa] = __builtin_amdgcn_mfma_f32_16x16x32_bf16(pA[qa][0], ones, L[qa], 0, 0, 0);
                L[qa] = __builtin_amdgcn_mfma_f32_16x16x32_bf16(pA[qa][1], ones, L[qa], 0, 0, 0);
            }
            #pragma unroll
            for (int fo = 0; fo < 4; ++fo) {
                const u16* vrow = &Vs[cur][(fo * 16 + l15) * 64];
                short8 vb0 = *(const short8*)(vrow + (quad ^ vsig) * 8);
                short8 vb1 = *(const short8*)(vrow + ((4 + quad) ^ vsig) * 8);
                #pragma unroll
                for (int pa = 0; pa < 2; ++pa) {
                    O[pa][fo] = __builtin_amdgcn_mfma_f32_16x16x32_bf16(pA[pa][0], vb0, O[pa][fo], 0, 0, 0);
                    O[pa][fo] = __builtin_amdgcn_mfma_f32_16x16x32_bf16(pA[pa][1], vb1, O[pa][fo], 0, 0, 0);
                }
            }
        }
        __syncthreads();
    }

    if (hf < 0) {
        #pragma unroll
        for (int pa = 0; pa < 2; ++pa)
            #pragma unroll
            for (int fo = 0; fo < 4; ++fo)
                #pragma unroll
                for (int r = 0; r < 4; ++r) {
                    int s = q0 + wq0 + pa * 16 + quad * 4 + r;
                    out[((size_t)b * SEQ + s) * 1024 + h * DH + fo * 16 + l15] =
                        O[pa][fo][r] / L[pa][r];
                }
    } else {
        const int pi = (qt - 8) * 2 + hf;
        u16* op = Opart + (((size_t)pi * 32 + bhx) * 128) * 64;
        float* lp = Lpart + ((size_t)pi * 32 + bhx) * 128;
        #pragma unroll
        for (int pa = 0; pa < 2; ++pa) {
            #pragma unroll
            for (int fo = 0; fo < 4; ++fo)
                #pragma unroll
                for (int r = 0; r < 4; ++r) {
                    int ql = wq0 + pa * 16 + quad * 4 + r;
                    op[(size_t)ql * 64 + fo * 16 + l15] = f2bf(O[pa][fo][r]);
                }
            if (l15 == 0) {
                #pragma unroll
                for (int r = 0; r < 4; ++r)
                    lp[wq0 + pa * 16 + quad * 4 + r] = L[pa][r];
            }
        }
    }
}

// ---- combine split partials: out = (O0+O1)/(l0+l1) ----
__global__ __launch_bounds__(256) void combine_kernel(
    const u16* __restrict__ Opart, const float* __restrict__ Lpart,
    float* __restrict__ out)
{
    int blk = blockIdx.x;            // 0..255
    int qt = 8 + (blk >> 5);
    int bh = blk & 31;
    int b = bh >> 4, h = bh & 15;
    int pi0 = (qt - 8) * 2, pi1 = pi0 + 1;
    int tid = threadIdx.x;
    int q = tid >> 1, seg = (tid & 1) * 32;
    const u16* o0 = Opart + (((size_t)pi0 * 32 + bh) * 128 + q) * 64 + seg;
    const u16* o1 = Opart + (((size_t)pi1 * 32 + bh) * 128 + q) * 64 + seg;
    float inv = 1.0f / (Lpart[((size_t)pi0 * 32 + bh) * 128 + q] +
                        Lpart[((size_t)pi1 * 32 + bh) * 128 + q]);
    float* op = out + ((size_t)b * SEQ + qt * 128 + q) * 1024 + h * DH + seg;
    #pragma unroll
    for (int d = 0; d < 32; d += 4) {
        union { uint2 d2; u16 u[4]; } a, c;
        a.d2 = *(const uint2*)(o0 + d);
        c.d2 = *(const uint2*)(o1 + d);
        float4 v;
        v.x = (bf2f(a.u[0]) + bf2f(c.u[0])) * inv;
        v.y = (bf2f(a.u[1]) + bf2f(c.u[1])) * inv;
        v.z = (bf2f(a.u[2]) + bf2f(c.u[2])) * inv;
        v.w = (bf2f(a.u[3]) + bf2f(c.u[3])) * inv;
        *(float4*)(op + d) = v;
    }
}

extern "C" void kernel_launch(void* const* d_in, const int* in_sizes, int n_in,
                              void* d_out, int out_size, void* d_ws, size_t ws_size,
                              hipStream_t stream) {
    const float* x  = (const float*)d_in[0];
    const float* Wq = (const float*)d_in[1];
    const float* bq = (const float*)d_in[2];
    const float* Wk = (const float*)d_in[3];
    const float* bk = (const float*)d_in[4];
    const float* Wv = (const float*)d_in[5];
    const float* bv = (const float*)d_in[6];
    float* out = (float*)d_out;

    const size_t NX = (size_t)BATCH * SEQ * D_IN;    // 4M
    const size_t NW = (size_t)3 * D_IN * 1024;       // 3M
    const size_t NP = (size_t)BATCH * NH * SEQ * DH; // 4M
    u16* xb = (u16*)d_ws;
    u16* WT = xb + NX;
    u16* Qb = WT + NW;
    u16* Kb = Qb + NP;
    u16* Vt = Kb + NP;
    // partials alias xb/WT (dead after qkv_gemm): Opart 8 MB, Lpart 256 KB
    u16* Opart = xb;
    float* Lpart = (float*)(xb + NX);    // = WT start

    prep_kernel<<<4096 + 768, 256, 0, stream>>>(x, Wq, Wk, Wv, xb, WT);
    qkv_gemm_kernel<<<dim3(24, 32), 256, 0, stream>>>(xb, WT, bq, bk, bv, Qb, Kb, Vt);
    flash_mfma_kernel<<<dim3(32, 24), 256, 0, stream>>>(Qb, Kb, Vt, out, Opart, Lpart);
    combine_kernel<<<256, 256, 0, stream>>>(Opart, Lpart, out);
}